// Round 1
// baseline (936.408 us; speedup 1.0000x reference)
//
#include <hip/hip_runtime.h>

#define ENT_DIM 128
#define BATCH 262144
#define MARGIN 1.0f
#define EPS 1e-6f

__global__ void zero_out_kernel(float* out) {
    out[0] = 0.0f;
}

__global__ __launch_bounds__(256) void transd_kernel(
    const float* __restrict__ ent_emb,
    const float* __restrict__ ent_map,
    const float* __restrict__ rel_emb,
    const float* __restrict__ rel_map,
    const int* __restrict__ pos_x,
    const int* __restrict__ neg_x,
    float* __restrict__ out)
{
    const int lane = threadIdx.x & 63;
    const int wid  = threadIdx.x >> 6;
    const int gwave  = blockIdx.x * 4 + wid;
    const int nwaves = gridDim.x * 4;

    float acc = 0.0f;

    for (int i = gwave; i < BATCH; i += nwaves) {
        // Force wave-uniform index into an SGPR so triple loads are scalar
        const int ib = __builtin_amdgcn_readfirstlane(i);

        const int ph = pos_x[3 * ib + 0];
        const int pr = pos_x[3 * ib + 1];
        const int pt = pos_x[3 * ib + 2];
        const int nh = neg_x[3 * ib + 0];
        const int nr = neg_x[3 * ib + 1];
        const int nt = neg_x[3 * ib + 2];

        // Each lane loads float2 -> full 512B row per wave load, coalesced
        const float2 phe = ((const float2*)(ent_emb + (size_t)ph * ENT_DIM))[lane];
        const float2 phm = ((const float2*)(ent_map + (size_t)ph * ENT_DIM))[lane];
        const float2 pte = ((const float2*)(ent_emb + (size_t)pt * ENT_DIM))[lane];
        const float2 ptm = ((const float2*)(ent_map + (size_t)pt * ENT_DIM))[lane];
        const float2 pre = ((const float2*)(rel_emb + (size_t)pr * ENT_DIM))[lane];
        const float2 prm = ((const float2*)(rel_map + (size_t)pr * ENT_DIM))[lane];

        const float2 nhe = ((const float2*)(ent_emb + (size_t)nh * ENT_DIM))[lane];
        const float2 nhm = ((const float2*)(ent_map + (size_t)nh * ENT_DIM))[lane];
        const float2 nte = ((const float2*)(ent_emb + (size_t)nt * ENT_DIM))[lane];
        const float2 ntm = ((const float2*)(ent_map + (size_t)nt * ENT_DIM))[lane];
        const float2 nre = ((const float2*)(rel_emb + (size_t)nr * ENT_DIM))[lane];
        const float2 nrm = ((const float2*)(rel_map + (size_t)nr * ENT_DIM))[lane];

        // Per-lane partial dot products
        float dph = phm.x * phe.x + phm.y * phe.y;   // dot(headp, head) pos
        float dpt = ptm.x * pte.x + ptm.y * pte.y;   // dot(tailp, tail) pos
        float dnh = nhm.x * nhe.x + nhm.y * nhe.y;   // neg
        float dnt = ntm.x * nte.x + ntm.y * nte.y;   // neg

        // 64-lane butterfly reduction of all 4 dots together
        #pragma unroll
        for (int off = 32; off >= 1; off >>= 1) {
            dph += __shfl_xor(dph, off);
            dpt += __shfl_xor(dpt, off);
            dnh += __shfl_xor(dnh, off);
            dnt += __shfl_xor(dnt, off);
        }

        // d = (relp*dot_h + head) + rel - (relp*dot_t + tail) + EPS, per component
        float dpx = prm.x * dph + phe.x + pre.x - (prm.x * dpt + pte.x) + EPS;
        float dpy = prm.y * dph + phe.y + pre.y - (prm.y * dpt + pte.y) + EPS;
        float dnx = nrm.x * dnh + nhe.x + nre.x - (nrm.x * dnt + nte.x) + EPS;
        float dny = nrm.y * dnh + nhe.y + nre.y - (nrm.y * dnt + nte.y) + EPS;

        float sp = dpx * dpx + dpy * dpy;
        float sn = dnx * dnx + dny * dny;

        #pragma unroll
        for (int off = 32; off >= 1; off >>= 1) {
            sp += __shfl_xor(sp, off);
            sn += __shfl_xor(sn, off);
        }

        float v = sqrtf(sp) - sqrtf(sn) + MARGIN;
        acc += fmaxf(v, 0.0f);
    }

    // Block reduction: 4 waves -> 1 atomic per block
    __shared__ float wsum[4];
    if (lane == 0) wsum[wid] = acc;
    __syncthreads();
    if (threadIdx.x == 0) {
        float s = wsum[0] + wsum[1] + wsum[2] + wsum[3];
        atomicAdd(out, s * (1.0f / (float)BATCH));
    }
}

extern "C" void kernel_launch(void* const* d_in, const int* in_sizes, int n_in,
                              void* d_out, int out_size, void* d_ws, size_t ws_size,
                              hipStream_t stream) {
    const float* ent_emb     = (const float*)d_in[0];
    const float* ent_map_emb = (const float*)d_in[1];
    const float* rel_emb     = (const float*)d_in[2];
    const float* rel_map_emb = (const float*)d_in[3];
    const int*   pos_x       = (const int*)d_in[4];
    const int*   neg_x       = (const int*)d_in[5];
    float* out = (float*)d_out;

    hipLaunchKernelGGL(zero_out_kernel, dim3(1), dim3(1), 0, stream, out);

    // 4096 blocks x 4 waves = 16384 waves; 16 pairs per wave (grid-stride)
    hipLaunchKernelGGL(transd_kernel, dim3(4096), dim3(256), 0, stream,
                       ent_emb, ent_map_emb, rel_emb, rel_map_emb,
                       pos_x, neg_x, out);
}